// Round 4
// baseline (5046.207 us; speedup 1.0000x reference)
//
#include <hip/hip_runtime.h>
#include <hip/hip_fp16.h>
#include <string.h>

// Problem constants (match reference)
constexpr int B = 64, T = 512, I = 512, H = 512, G = 2048; // G = 4*H

typedef _Float16 half8 __attribute__((ext_vector_type(8)));
typedef float floatx4 __attribute__((ext_vector_type(4)));

// ---------------------------------------------------------------------------
// Phase 1: xg[t][g][b] = sum_i x[b][t][i] * W_ih[g][i] + (b_ih[g] + b_hh[g])
// stored as f16. MFMA f16, A = W_ih rows (registers), B = x_t (LDS).
// Each wave owns TWO 16-row M-tiles (block = 128 rows) to halve x re-reads.
// grid: (16 row-tiles of 128 rows, 128 t-groups of 4 t), block 256.
// ---------------------------------------------------------------------------
__global__ __launch_bounds__(256, 2) void xg_gemm(
    const float* __restrict__ x,     // [B][T][I]
    const float* __restrict__ W_ih,  // [G][I]
    const float* __restrict__ b_ih,
    const float* __restrict__ b_hh,
    _Float16* __restrict__ xg)       // [T][G][B]
{
    const int tid  = threadIdx.x;
    const int wave = tid >> 6, lane = tid & 63;
    const int quad = lane >> 4, col = lane & 15;
    const int rowA = blockIdx.x * 128 + wave * 16; // first 16-row M-tile
    const int rowB = rowA + 64;                    // second 16-row M-tile

    __shared__ __align__(16) _Float16 xs[64][264]; // 64 b x 256 k (half of K), padded

    // A-fragments: lane holds A[m=col][k = kc*32 + quad*8 + j], j=0..8
    half8 wfA[16], wfB[16];
    {
        const float* wpA = W_ih + (size_t)(rowA + col) * I;
        const float* wpB = W_ih + (size_t)(rowB + col) * I;
#pragma unroll
        for (int kc = 0; kc < 16; ++kc) {
            half8 vA, vB;
#pragma unroll
            for (int j = 0; j < 8; ++j) {
                vA[j] = (_Float16)wpA[kc * 32 + quad * 8 + j];
                vB[j] = (_Float16)wpB[kc * 32 + quad * 8 + j];
            }
            wfA[kc] = vA; wfB[kc] = vB;
        }
    }
    // bias for epilogue rows (C: m = quad*4 + r)
    float biasA[4], biasB[4];
#pragma unroll
    for (int r = 0; r < 4; ++r) {
        biasA[r] = b_ih[rowA + quad * 4 + r] + b_hh[rowA + quad * 4 + r];
        biasB[r] = b_ih[rowB + quad * 4 + r] + b_hh[rowB + quad * 4 + r];
    }

    for (int ti = 0; ti < 4; ++ti) {
        const int t = blockIdx.y * 4 + ti;
        floatx4 accA[4], accB[4];
#pragma unroll
        for (int nt = 0; nt < 4; ++nt) {
            accA[nt] = (floatx4){0.f, 0.f, 0.f, 0.f};
            accB[nt] = (floatx4){0.f, 0.f, 0.f, 0.f};
        }

        for (int hfl = 0; hfl < 2; ++hfl) {
            __syncthreads(); // protect xs from previous readers
            // stage x[b][t][hfl*256 .. +256] -> xs (f16). 16384 floats.
#pragma unroll 4
            for (int c = 0; c < 16; ++c) {
                int idx = c * 256 + tid;     // float4 index
                int row = idx >> 6;          // batch 0..63
                int kk  = (idx & 63) * 4;    // 0..252
                const float4 v = *(const float4*)(x + ((size_t)row * T + t) * I + hfl * 256 + kk);
                xs[row][kk + 0] = (_Float16)v.x;
                xs[row][kk + 1] = (_Float16)v.y;
                xs[row][kk + 2] = (_Float16)v.z;
                xs[row][kk + 3] = (_Float16)v.w;
            }
            __syncthreads();
#pragma unroll
            for (int kc = 0; kc < 8; ++kc) {
#pragma unroll
                for (int nt = 0; nt < 4; ++nt) {
                    const half8 bfr = *(const half8*)&xs[nt * 16 + col][kc * 32 + quad * 8];
                    accA[nt] = __builtin_amdgcn_mfma_f32_16x16x32_f16(
                        wfA[hfl * 8 + kc], bfr, accA[nt], 0, 0, 0);
                    accB[nt] = __builtin_amdgcn_mfma_f32_16x16x32_f16(
                        wfB[hfl * 8 + kc], bfr, accB[nt], 0, 0, 0);
                }
            }
        }
        // epilogue: C[m = quad*4+r][n = col] per N-tile, both M-tiles
#pragma unroll
        for (int nt = 0; nt < 4; ++nt) {
            int b = nt * 16 + col;
#pragma unroll
            for (int r = 0; r < 4; ++r) {
                xg[((size_t)t * G + rowA + quad * 4 + r) * B + b] = (_Float16)(accA[nt][r] + biasA[r]);
                xg[((size_t)t * G + rowB + quad * 4 + r) * B + b] = (_Float16)(accB[nt][r] + biasB[r]);
            }
        }
    }
}

// ---------------------------------------------------------------------------
// Phase 2: persistent recurrence. 64 blocks x 256 threads, wave-autonomous.
// Sync: 256 per-wave epoch flags (no atomic RMW, no __syncthreads in loop).
//   producer wave: h stores (sc1 relaxed 8B), s_waitcnt vmcnt(0),
//                  lane0 stores flag[gwave] = epoch (plain sc1 dword store).
//   consumer wave: poll -- lane l reads flag qwords 2l,2l+1 (64 lanes cover
//                  all 256 flags, one coalesced 1KB read), exit when
//                  __all(min >= epoch). Then sc1 h loads straight from LLC.
// Anti-clobber: a wave's vmcnt(0) before its flag store also drains its h
// READS, so hbuf[x] is never overwritten before every reader of the previous
// epoch finished reading it.
// ---------------------------------------------------------------------------
__global__ __launch_bounds__(256, 1) void lstm_rec(
    const float* __restrict__ h0,    // [B][H]
    const float* __restrict__ c0,    // [B][H]
    const float* __restrict__ W_hh,  // [G][H]
    const _Float16* __restrict__ xg, // [T][G][B]
    _Float16* __restrict__ hbuf,     // [2][B][H]
    unsigned int* __restrict__ flags,// 256 entries, zeroed by memset
    float* __restrict__ out)         // [B][T][H] ++ hT[B][H] ++ cT[B][H]
{
    const int s   = blockIdx.x;
    const int hs  = s * 8;
    const int tid = threadIdx.x;
    const int wave = tid >> 6, lane = tid & 63;
    const int quad = lane >> 4, col = lane & 15;
    const int b = wave * 16 + col;
    const int gwave = s * 4 + wave;

    // A-fragment row for this lane (m = col):
    int arow0 = (col < 8) ? (hs + col) : (512 + hs + col - 8);   // i / f
    int arow1 = arow0 + 1024;                                    // g / o
    half8 wf0[16], wf1[16];
#pragma unroll
    for (int kc = 0; kc < 16; ++kc) {
        const float* p0 = W_hh + (size_t)arow0 * H + kc * 32 + quad * 8;
        const float* p1 = W_hh + (size_t)arow1 * H + kc * 32 + quad * 8;
        half8 v0, v1;
#pragma unroll
        for (int j = 0; j < 8; ++j) { v0[j] = (_Float16)p0[j]; v1[j] = (_Float16)p1[j]; }
        wf0[kc] = v0; wf1[kc] = v1;
    }

    // C rows this lane holds: local row lr = quad*4+r.
    int xrow0[4], xrow1[4];
#pragma unroll
    for (int r = 0; r < 4; ++r) {
        int lr = quad * 4 + r;
        xrow0[r] = (lr < 8) ? (hs + lr) : (512 + hs + lr - 8);
        xrow1[r] = xrow0[r] + 1024;
    }

    // After the xor-32 exchange, this lane updates h-index jj = (quad&1)*4 + r.
    float c[4];
#pragma unroll
    for (int r = 0; r < 4; ++r) {
        int jj = (quad & 1) * 4 + r;
        c[r] = c0[(size_t)b * H + hs + jj];
    }

    // init h buffer 0 with h0: one 8B agent-relaxed store per (quad<2) lane
    if (quad < 2) {
        _Float16 v4[4];
#pragma unroll
        for (int r = 0; r < 4; ++r)
            v4[r] = (_Float16)h0[(size_t)b * H + hs + (quad & 1) * 4 + r];
        unsigned long long uv; __builtin_memcpy(&uv, v4, 8);
        __hip_atomic_store((unsigned long long*)(hbuf + (size_t)b * H + hs + (quad & 1) * 4),
                           uv, __ATOMIC_RELAXED, __HIP_MEMORY_SCOPE_AGENT);
    }
    asm volatile("s_waitcnt vmcnt(0)" ::: "memory");
    if (lane == 0)
        __hip_atomic_store(flags + gwave, 1u, __ATOMIC_RELAXED, __HIP_MEMORY_SCOPE_AGENT);

    // prefetch xg for t=0 (plain cached loads; xg is constant during phase 2)
    float xp0[4], xp1[4];
#pragma unroll
    for (int r = 0; r < 4; ++r) {
        xp0[r] = (float)xg[(size_t)xrow0[r] * B + b];
        xp1[r] = (float)xg[(size_t)xrow1[r] * B + b];
    }

    const unsigned long long* fq = (const unsigned long long*)flags; // 128 qwords
#define POLL_FLAGS(tgtval)                                                           \
    for (;;) {                                                                       \
        unsigned long long fa = __hip_atomic_load(fq + 2 * lane,     __ATOMIC_RELAXED, __HIP_MEMORY_SCOPE_AGENT); \
        unsigned long long fb = __hip_atomic_load(fq + 2 * lane + 1, __ATOMIC_RELAXED, __HIP_MEMORY_SCOPE_AGENT); \
        unsigned m0 = (unsigned)fa, m1 = (unsigned)(fa >> 32);                       \
        unsigned m2 = (unsigned)fb, m3 = (unsigned)(fb >> 32);                       \
        unsigned mn = min(min(m0, m1), min(m2, m3));                                 \
        if (__all(mn >= (tgtval))) break;                                            \
    }                                                                                \
    asm volatile("" ::: "memory");

    POLL_FLAGS(1u)

    float hh[4] = {0.f, 0.f, 0.f, 0.f};

    for (int t = 0; t < T; ++t) {
        const _Float16* hcur = hbuf + (size_t)(t & 1) * B * H;
        _Float16*       hnxt = hbuf + (size_t)((t + 1) & 1) * B * H;

        // ---- issue ALL coherent h loads first so they pipeline (one latency)
        unsigned long long hu0[16], hu1[16];
#pragma unroll
        for (int kc = 0; kc < 16; ++kc) {
            unsigned long long* hp =
                (unsigned long long*)(hcur + (size_t)b * H + kc * 32 + quad * 8);
            hu0[kc] = __hip_atomic_load(hp,     __ATOMIC_RELAXED, __HIP_MEMORY_SCOPE_AGENT);
            hu1[kc] = __hip_atomic_load(hp + 1, __ATOMIC_RELAXED, __HIP_MEMORY_SCOPE_AGENT);
        }

        // xg prefetch for t+1: issued early so it never lands in the poll wait
        float xn0[4], xn1[4];
        if (t + 1 < T) {
            const _Float16* xgt = xg + (size_t)(t + 1) * G * B;
#pragma unroll
            for (int r = 0; r < 4; ++r) {
                xn0[r] = (float)xgt[(size_t)xrow0[r] * B + b];
                xn1[r] = (float)xgt[(size_t)xrow1[r] * B + b];
            }
        }

        floatx4 acc0 = (floatx4){0.f, 0.f, 0.f, 0.f};
        floatx4 acc1 = (floatx4){0.f, 0.f, 0.f, 0.f};
#pragma unroll
        for (int kc = 0; kc < 16; ++kc) {
            half8 bfr;
            __builtin_memcpy(&bfr, &hu0[kc], 8);
            __builtin_memcpy((char*)&bfr + 8, &hu1[kc], 8);
            acc0 = __builtin_amdgcn_mfma_f32_16x16x32_f16(wf0[kc], bfr, acc0, 0, 0, 0);
            acc1 = __builtin_amdgcn_mfma_f32_16x16x32_f16(wf1[kc], bfr, acc1, 0, 0, 0);
        }

        // add prefetched xg, then exchange i/f and g/o halves across lane^32
        float p0[4], p1[4];
#pragma unroll
        for (int r = 0; r < 4; ++r) {
            p0[r] = acc0[r] + xp0[r];
            p1[r] = acc1[r] + xp1[r];
        }
        float e0[4], e1[4];
#pragma unroll
        for (int r = 0; r < 4; ++r) {
            e0[r] = __shfl_xor(p0[r], 32);
            e1[r] = __shfl_xor(p1[r], 32);
        }
#pragma unroll
        for (int r = 0; r < 4; ++r) {
            float iv = (quad < 2) ? p0[r] : e0[r];
            float fv = (quad < 2) ? e0[r] : p0[r];
            float gv = (quad < 2) ? p1[r] : e1[r];
            float ov = (quad < 2) ? e1[r] : p1[r];
            float ii = 1.f / (1.f + __expf(-iv));
            float ff = 1.f / (1.f + __expf(-fv));
            float eg = __expf(-2.f * gv);
            float gg = (1.f - eg) / (1.f + eg);
            float oo = 1.f / (1.f + __expf(-ov));
            float cn = ff * c[r] + ii * gg;
            c[r] = cn;
            float ec = __expf(-2.f * cn);
            hh[r] = oo * ((1.f - ec) / (1.f + ec));
        }
        if (quad < 2) {
            // h store: one 8B agent-relaxed store (sc1 -> LLC)
            _Float16 v4[4] = {(_Float16)hh[0], (_Float16)hh[1],
                              (_Float16)hh[2], (_Float16)hh[3]};
            unsigned long long uv; __builtin_memcpy(&uv, v4, 8);
            __hip_atomic_store((unsigned long long*)(hnxt + (size_t)b * H + hs + (quad & 1) * 4),
                               uv, __ATOMIC_RELAXED, __HIP_MEMORY_SCOPE_AGENT);
        }

        // ---- drain h stores (and h reads), then publish this wave's epoch
        asm volatile("s_waitcnt vmcnt(0)" ::: "memory");
        if (lane == 0)
            __hip_atomic_store(flags + gwave, (unsigned)(t + 2),
                               __ATOMIC_RELAXED, __HIP_MEMORY_SCOPE_AGENT);

        // out store: plain cached, AFTER the flag (off the critical path;
        // next step's vmcnt(0) will drain it long after it completed)
        if (quad < 2) {
            float* op = out + ((size_t)b * T + t) * H + hs + (quad & 1) * 4;
            op[0] = hh[0]; op[1] = hh[1]; op[2] = hh[2]; op[3] = hh[3];
        }

        // rotate xg prefetch registers
#pragma unroll
        for (int r = 0; r < 4; ++r) { xp0[r] = xn0[r]; xp1[r] = xn1[r]; }

        // ---- wait for all 256 waves to publish epoch t+2 (skip on last step)
        if (t + 1 < T) {
            const unsigned tgt = (unsigned)(t + 2);
            POLL_FLAGS(tgt)
        }
    }

    // final h_T, c_T
    if (quad < 2) {
        float* hT = out + (size_t)B * T * H;
        float* cT = hT + (size_t)B * H;
#pragma unroll
        for (int r = 0; r < 4; ++r) {
            int jj = (quad & 1) * 4 + r;
            hT[(size_t)b * H + hs + jj] = hh[r];
            cT[(size_t)b * H + hs + jj] = c[r];
        }
    }
#undef POLL_FLAGS
}

// ---------------------------------------------------------------------------
extern "C" void kernel_launch(void* const* d_in, const int* in_sizes, int n_in,
                              void* d_out, int out_size, void* d_ws, size_t ws_size,
                              hipStream_t stream) {
    const float* x    = (const float*)d_in[0];
    const float* h0   = (const float*)d_in[1];
    const float* c0   = (const float*)d_in[2];
    const float* W_ih = (const float*)d_in[3];
    const float* W_hh = (const float*)d_in[4];
    const float* b_ih = (const float*)d_in[5];
    const float* b_hh = (const float*)d_in[6];
    float* out = (float*)d_out;

    // workspace layout:
    //   [0, 2048)                    : 256 epoch flags (zeroed)
    //   [2048, 2048+2*B*H*2)         : h double buffer (f16)
    //   [133120, +T*G*B*2)           : xg (f16), 128 MiB
    unsigned int* flags = (unsigned int*)d_ws;
    _Float16* hbuf = (_Float16*)((char*)d_ws + 2048);
    _Float16* xg   = (_Float16*)((char*)d_ws + 2048 + (size_t)2 * B * H * 2);

    hipMemsetAsync(d_ws, 0, 2048, stream);

    xg_gemm<<<dim3(16, 128), 256, 0, stream>>>(x, W_ih, b_ih, b_hh, xg);
    lstm_rec<<<64, 256, 0, stream>>>(h0, c0, W_hh, xg, hbuf, flags, out);
}

// Round 5
// 3126.187 us; speedup vs baseline: 1.6142x; 1.6142x over previous
//
#include <hip/hip_runtime.h>
#include <hip/hip_fp16.h>
#include <string.h>

// Problem constants (match reference)
constexpr int B = 64, T = 512, I = 512, H = 512, G = 2048; // G = 4*H

typedef _Float16 half8 __attribute__((ext_vector_type(8)));
typedef float floatx4 __attribute__((ext_vector_type(4)));

// ---------------------------------------------------------------------------
// Phase 1: xg[t][g][b] = sum_i x[b][t][i] * W_ih[g][i] + (b_ih[g] + b_hh[g])
// stored as f16. (unchanged from R3)
// ---------------------------------------------------------------------------
__global__ __launch_bounds__(256, 2) void xg_gemm(
    const float* __restrict__ x,     // [B][T][I]
    const float* __restrict__ W_ih,  // [G][I]
    const float* __restrict__ b_ih,
    const float* __restrict__ b_hh,
    _Float16* __restrict__ xg)       // [T][G][B]
{
    const int tid  = threadIdx.x;
    const int wave = tid >> 6, lane = tid & 63;
    const int quad = lane >> 4, col = lane & 15;
    const int rowA = blockIdx.x * 128 + wave * 16;
    const int rowB = rowA + 64;

    __shared__ __align__(16) _Float16 xs[64][264];

    half8 wfA[16], wfB[16];
    {
        const float* wpA = W_ih + (size_t)(rowA + col) * I;
        const float* wpB = W_ih + (size_t)(rowB + col) * I;
#pragma unroll
        for (int kc = 0; kc < 16; ++kc) {
            half8 vA, vB;
#pragma unroll
            for (int j = 0; j < 8; ++j) {
                vA[j] = (_Float16)wpA[kc * 32 + quad * 8 + j];
                vB[j] = (_Float16)wpB[kc * 32 + quad * 8 + j];
            }
            wfA[kc] = vA; wfB[kc] = vB;
        }
    }
    float biasA[4], biasB[4];
#pragma unroll
    for (int r = 0; r < 4; ++r) {
        biasA[r] = b_ih[rowA + quad * 4 + r] + b_hh[rowA + quad * 4 + r];
        biasB[r] = b_ih[rowB + quad * 4 + r] + b_hh[rowB + quad * 4 + r];
    }

    for (int ti = 0; ti < 4; ++ti) {
        const int t = blockIdx.y * 4 + ti;
        floatx4 accA[4], accB[4];
#pragma unroll
        for (int nt = 0; nt < 4; ++nt) {
            accA[nt] = (floatx4){0.f, 0.f, 0.f, 0.f};
            accB[nt] = (floatx4){0.f, 0.f, 0.f, 0.f};
        }

        for (int hfl = 0; hfl < 2; ++hfl) {
            __syncthreads();
#pragma unroll 4
            for (int c = 0; c < 16; ++c) {
                int idx = c * 256 + tid;
                int row = idx >> 6;
                int kk  = (idx & 63) * 4;
                const float4 v = *(const float4*)(x + ((size_t)row * T + t) * I + hfl * 256 + kk);
                xs[row][kk + 0] = (_Float16)v.x;
                xs[row][kk + 1] = (_Float16)v.y;
                xs[row][kk + 2] = (_Float16)v.z;
                xs[row][kk + 3] = (_Float16)v.w;
            }
            __syncthreads();
#pragma unroll
            for (int kc = 0; kc < 8; ++kc) {
#pragma unroll
                for (int nt = 0; nt < 4; ++nt) {
                    const half8 bfr = *(const half8*)&xs[nt * 16 + col][kc * 32 + quad * 8];
                    accA[nt] = __builtin_amdgcn_mfma_f32_16x16x32_f16(
                        wfA[hfl * 8 + kc], bfr, accA[nt], 0, 0, 0);
                    accB[nt] = __builtin_amdgcn_mfma_f32_16x16x32_f16(
                        wfB[hfl * 8 + kc], bfr, accB[nt], 0, 0, 0);
                }
            }
        }
#pragma unroll
        for (int nt = 0; nt < 4; ++nt) {
            int b = nt * 16 + col;
#pragma unroll
            for (int r = 0; r < 4; ++r) {
                xg[((size_t)t * G + rowA + quad * 4 + r) * B + b] = (_Float16)(accA[nt][r] + biasA[r]);
                xg[((size_t)t * G + rowB + quad * 4 + r) * B + b] = (_Float16)(accB[nt][r] + biasB[r]);
            }
        }
    }
}

// ---------------------------------------------------------------------------
// Phase 2: batch-partitioned persistent recurrence. 64 blocks x 256 threads,
// organized as 4 batch-groups (bg = blockIdx&3, 16 batches each) x 16
// H-slices (hg = blockIdx>>2, 32 h-indices each). The recurrence is
// independent per batch, so sync + h-exchange stay WITHIN the 16-block
// group (blocks {bg, bg+4, ...} -> spans only 2 XCDs under round-robin
// dispatch). Sync = R3-style per-group single-line counter: per-wave
// vmcnt(0) drain, __syncthreads, one relaxed atomic add by tid0, all
// threads spin on one relaxed sc1 load (single cacheline, broadcast).
// h lives in a per-group 16KB double buffer, accessed only with
// agent-scope relaxed atomics (sc1 <-> LLC, no cache maintenance anywhere).
// ---------------------------------------------------------------------------
__global__ __launch_bounds__(256, 1) void lstm_rec(
    const float* __restrict__ h0,    // [B][H]
    const float* __restrict__ c0,    // [B][H]
    const float* __restrict__ W_hh,  // [G][H]
    const _Float16* __restrict__ xg, // [T][G][B]
    _Float16* __restrict__ hbuf,     // [2][4][16][512] f16
    unsigned int* __restrict__ cnts, // 4 counters, 256B apart, zeroed
    float* __restrict__ out)         // [B][T][H] ++ hT[B][H] ++ cT[B][H]
{
    const int blk  = blockIdx.x;
    const int bg   = blk & 3;        // batch group (16 batches)
    const int hg   = blk >> 2;       // H slice (32 h-indices)
    const int tid  = threadIdx.x;
    const int wave = tid >> 6, lane = tid & 63;
    const int quad = lane >> 4, col = lane & 15;

    const int bglob = bg * 16 + col;       // this lane's batch (N = col)
    const int hbase = hg * 32 + wave * 8;  // this wave's 8 h-indices

    unsigned int* cnt = cnts + bg * 64;    // 256B-separated per-group counter

    // A-fragment rows (m = col): tile0 = [i(8), f(8)], tile1 = [g(8), o(8)]
    int arow0 = (col < 8) ? (hbase + col) : (512 + hbase + col - 8);
    int arow1 = arow0 + 1024;
    half8 wf0[16], wf1[16];
#pragma unroll
    for (int kc = 0; kc < 16; ++kc) {
        const float* p0 = W_hh + (size_t)arow0 * H + kc * 32 + quad * 8;
        const float* p1 = W_hh + (size_t)arow1 * H + kc * 32 + quad * 8;
        half8 v0, v1;
#pragma unroll
        for (int j = 0; j < 8; ++j) { v0[j] = (_Float16)p0[j]; v1[j] = (_Float16)p1[j]; }
        wf0[kc] = v0; wf1[kc] = v1;
    }

    // C rows this lane holds (lr = quad*4+r): xg row indices
    int xrow0[4], xrow1[4];
#pragma unroll
    for (int r = 0; r < 4; ++r) {
        int lr = quad * 4 + r;
        xrow0[r] = (lr < 8) ? (hbase + lr) : (512 + hbase + lr - 8);
        xrow1[r] = xrow0[r] + 1024;
    }

    // After xor-32 exchange this lane updates h-index hbase + (quad&1)*4 + r
    float c[4];
#pragma unroll
    for (int r = 0; r < 4; ++r)
        c[r] = c0[(size_t)bglob * H + hbase + (quad & 1) * 4 + r];

    // group h double buffer: hbuf[buf][bg][16][512]
    _Float16* hb0 = hbuf + ((size_t)0 * 4 + bg) * 16 * 512;
    _Float16* hb1 = hbuf + ((size_t)1 * 4 + bg) * 16 * 512;

    // init buffer 0 with h0 (each (bg,h) written once by its owner wave)
    if (quad < 2) {
        _Float16 v4[4];
#pragma unroll
        for (int r = 0; r < 4; ++r)
            v4[r] = (_Float16)h0[(size_t)bglob * H + hbase + (quad & 1) * 4 + r];
        unsigned long long uv; __builtin_memcpy(&uv, v4, 8);
        __hip_atomic_store((unsigned long long*)(hb0 + (size_t)col * 512 + hbase + (quad & 1) * 4),
                           uv, __ATOMIC_RELAXED, __HIP_MEMORY_SCOPE_AGENT);
    }
    asm volatile("s_waitcnt vmcnt(0)" ::: "memory");
    __syncthreads();
    if (tid == 0)
        __hip_atomic_fetch_add(cnt, 1u, __ATOMIC_RELAXED, __HIP_MEMORY_SCOPE_AGENT);

    // prefetch xg for t=0 (plain cached loads; xg is constant during phase 2)
    float xp0[4], xp1[4];
#pragma unroll
    for (int r = 0; r < 4; ++r) {
        xp0[r] = (float)xg[(size_t)xrow0[r] * B + bglob];
        xp1[r] = (float)xg[(size_t)xrow1[r] * B + bglob];
    }

    while (__hip_atomic_load(cnt, __ATOMIC_RELAXED, __HIP_MEMORY_SCOPE_AGENT) < 16u) {}
    asm volatile("" ::: "memory");

    float hh[4] = {0.f, 0.f, 0.f, 0.f};

    for (int t = 0; t < T; ++t) {
        const _Float16* hcur = (t & 1) ? hb1 : hb0;
        _Float16*       hnxt = (t & 1) ? hb0 : hb1;

        // issue all coherent h loads first so they pipeline (one latency)
        unsigned long long hu0[16], hu1[16];
#pragma unroll
        for (int kc = 0; kc < 16; ++kc) {
            unsigned long long* hp =
                (unsigned long long*)(hcur + (size_t)col * 512 + kc * 32 + quad * 8);
            hu0[kc] = __hip_atomic_load(hp,     __ATOMIC_RELAXED, __HIP_MEMORY_SCOPE_AGENT);
            hu1[kc] = __hip_atomic_load(hp + 1, __ATOMIC_RELAXED, __HIP_MEMORY_SCOPE_AGENT);
        }

        floatx4 acc0 = (floatx4){0.f, 0.f, 0.f, 0.f};
        floatx4 acc1 = (floatx4){0.f, 0.f, 0.f, 0.f};
#pragma unroll
        for (int kc = 0; kc < 16; ++kc) {
            half8 bfr;
            __builtin_memcpy(&bfr, &hu0[kc], 8);
            __builtin_memcpy((char*)&bfr + 8, &hu1[kc], 8);
            acc0 = __builtin_amdgcn_mfma_f32_16x16x32_f16(wf0[kc], bfr, acc0, 0, 0, 0);
            acc1 = __builtin_amdgcn_mfma_f32_16x16x32_f16(wf1[kc], bfr, acc1, 0, 0, 0);
        }

        // add prefetched xg, exchange i/f and g/o halves across lane^32
        float p0[4], p1[4];
#pragma unroll
        for (int r = 0; r < 4; ++r) {
            p0[r] = acc0[r] + xp0[r];
            p1[r] = acc1[r] + xp1[r];
        }
        float e0[4], e1[4];
#pragma unroll
        for (int r = 0; r < 4; ++r) {
            e0[r] = __shfl_xor(p0[r], 32);
            e1[r] = __shfl_xor(p1[r], 32);
        }
#pragma unroll
        for (int r = 0; r < 4; ++r) {
            float iv = (quad < 2) ? p0[r] : e0[r];
            float fv = (quad < 2) ? e0[r] : p0[r];
            float gv = (quad < 2) ? p1[r] : e1[r];
            float ov = (quad < 2) ? e1[r] : p1[r];
            float ii = 1.f / (1.f + __expf(-iv));
            float ff = 1.f / (1.f + __expf(-fv));
            float eg = __expf(-2.f * gv);
            float gg = (1.f - eg) / (1.f + eg);
            float oo = 1.f / (1.f + __expf(-ov));
            float cn = ff * c[r] + ii * gg;
            c[r] = cn;
            float ec = __expf(-2.f * cn);
            hh[r] = oo * ((1.f - ec) / (1.f + ec));
        }
        if (quad < 2) {
            // h store: one 8B agent-relaxed store (sc1 -> LLC)
            _Float16 v4[4] = {(_Float16)hh[0], (_Float16)hh[1],
                              (_Float16)hh[2], (_Float16)hh[3]};
            unsigned long long uv; __builtin_memcpy(&uv, v4, 8);
            __hip_atomic_store((unsigned long long*)(hnxt + (size_t)col * 512 + hbase + (quad & 1) * 4),
                               uv, __ATOMIC_RELAXED, __HIP_MEMORY_SCOPE_AGENT);
            // out store: plain cached (drained by the same vmcnt below)
            float* op = out + ((size_t)bglob * T + t) * H + hbase + (quad & 1) * 4;
            op[0] = hh[0]; op[1] = hh[1]; op[2] = hh[2]; op[3] = hh[3];
        }

        // ---- group barrier: drain, signal once per block, spin on one line
        asm volatile("s_waitcnt vmcnt(0)" ::: "memory");
        __syncthreads();
        if (tid == 0)
            __hip_atomic_fetch_add(cnt, 1u, __ATOMIC_RELAXED, __HIP_MEMORY_SCOPE_AGENT);

        // prefetch xg for t+1 while the counter propagates
        if (t + 1 < T) {
            const _Float16* xgt = xg + (size_t)(t + 1) * G * B;
#pragma unroll
            for (int r = 0; r < 4; ++r) {
                xp0[r] = (float)xgt[(size_t)xrow0[r] * B + bglob];
                xp1[r] = (float)xgt[(size_t)xrow1[r] * B + bglob];
            }
            const unsigned int tgt = 16u * (unsigned)(t + 2);
            while (__hip_atomic_load(cnt, __ATOMIC_RELAXED, __HIP_MEMORY_SCOPE_AGENT) < tgt) {}
            asm volatile("" ::: "memory");
        }
    }

    // final h_T, c_T
    if (quad < 2) {
        float* hT = out + (size_t)B * T * H;
        float* cT = hT + (size_t)B * H;
#pragma unroll
        for (int r = 0; r < 4; ++r) {
            int jj = (quad & 1) * 4 + r;
            hT[(size_t)bglob * H + hbase + jj] = hh[r];
            cT[(size_t)bglob * H + hbase + jj] = c[r];
        }
    }
}

// ---------------------------------------------------------------------------
extern "C" void kernel_launch(void* const* d_in, const int* in_sizes, int n_in,
                              void* d_out, int out_size, void* d_ws, size_t ws_size,
                              hipStream_t stream) {
    const float* x    = (const float*)d_in[0];
    const float* h0   = (const float*)d_in[1];
    const float* c0   = (const float*)d_in[2];
    const float* W_ih = (const float*)d_in[3];
    const float* W_hh = (const float*)d_in[4];
    const float* b_ih = (const float*)d_in[5];
    const float* b_hh = (const float*)d_in[6];
    float* out = (float*)d_out;

    // workspace layout:
    //   [0, 2048)                 : 4 group counters (256B apart), zeroed
    //   [2048, +2*4*16*512*2)     : h double buffer (f16), 128KB
    //   [next, +T*G*B*2)          : xg (f16), 128 MiB
    unsigned int* cnts = (unsigned int*)d_ws;
    _Float16* hbuf = (_Float16*)((char*)d_ws + 2048);
    _Float16* xg   = (_Float16*)((char*)d_ws + 2048 + (size_t)2 * 4 * 16 * 512 * 2);

    hipMemsetAsync(d_ws, 0, 2048, stream);

    xg_gemm<<<dim3(16, 128), 256, 0, stream>>>(x, W_ih, b_ih, b_hh, xg);
    lstm_rec<<<64, 256, 0, stream>>>(h0, c0, W_hh, xg, hbuf, cnts, out);
}